// Round 4
// baseline (454.845 us; speedup 1.0000x reference)
//
#include <hip/hip_runtime.h>
#include <math.h>

#define VOCAB 20000
#define E     300
#define EP    320          // padded K for proj GEMM (10 k-steps of 32)
#define H     1024
#define G     8
#define NOUT  300
#define NP    320          // padded N for outproj
#define KOUT  8192         // G*H
#define NANS  4000
#define B     64
#define NQ    32
#define NK    256

typedef __attribute__((ext_vector_type(8))) short bf16x8;
typedef __attribute__((ext_vector_type(4))) float f32x4;

__device__ inline ushort f2bf(float x) {
    union { float f; unsigned u; } c; c.f = x;
    unsigned r = c.u + 0x7FFF + ((c.u >> 16) & 1);   // RNE
    return (ushort)(r >> 16);
}
__device__ inline float bf2f(ushort x) {
    union { unsigned u; float f; } c; c.u = ((unsigned)x) << 16;
    return c.f;
}
#define MFMA(a, b, c) __builtin_amdgcn_mfma_f32_16x16x32_bf16((a), (b), (c), 0, 0, 0)

// ---------------------------------------------------------------------------
// P0: WT[h][e] (bf16, e padded to 320) from W[e][h] f32.  grid (16, 2)
// ---------------------------------------------------------------------------
__global__ __launch_bounds__(256) void prep_wt(
    const float* __restrict__ Wq, const float* __restrict__ Wk,
    ushort* __restrict__ WTq, ushort* __restrict__ WTk)
{
    const float* W = blockIdx.y ? Wk : Wq;
    ushort* WT = blockIdx.y ? WTk : WTq;
    const int h0 = blockIdx.x * 64;
    __shared__ ushort lds[64][EP + 8];
    for (int i = threadIdx.x; i < 64 * EP; i += 256) {
        int e = i / 64, hh = i % 64;                 // coalesced along h
        float v = (e < E) ? W[e * H + h0 + hh] : 0.f;
        lds[hh][e] = f2bf(v);
    }
    __syncthreads();
    for (int i = threadIdx.x; i < 64 * EP; i += 256) {
        int hh = i / EP, e = i % EP;                 // coalesced along e
        WT[(h0 + hh) * EP + e] = lds[hh][e];
    }
}

// ---------------------------------------------------------------------------
// P0b: woutT[n][k] bf16 (n padded to 320) from Wout[k][n] f32. grid (128, 5)
// ---------------------------------------------------------------------------
__global__ __launch_bounds__(256) void prep_woutT(
    const float* __restrict__ Wout, ushort* __restrict__ woutT)
{
    const int k0 = blockIdx.x * 64, n0 = blockIdx.y * 64;
    __shared__ ushort td[64][72];
    for (int i = threadIdx.x; i < 64 * 64; i += 256) {
        int kk = i >> 6, nn = i & 63;
        int n = n0 + nn;
        float v = (n < NOUT) ? Wout[(k0 + kk) * NOUT + n] : 0.f;
        td[nn][kk] = f2bf(v);
    }
    __syncthreads();
    for (int i = threadIdx.x; i < 64 * 8; i += 256) {
        int nn = i >> 3, c = i & 7;
        *(bf16x8*)(woutT + (n0 + nn) * KOUT + k0 + c * 8) =
            *(const bf16x8*)(&td[nn][c * 8]);
    }
}

// ---------------------------------------------------------------------------
// P1: MFMA gather-GEMM  out = emb[idx] @ W + bias   (M-tile 32, N-tile 256)
// MODE 0 (hq): also write hqw[b][g][q][d] = (out * Watt[d][g]) bf16
// MODE 1 (hk): also write hkT[b][d][k] bf16 via LDS transpose bounce
// ---------------------------------------------------------------------------
template <int MODE>
__global__ __launch_bounds__(256) void proj_mfma(
    const int* __restrict__ idx, const float* __restrict__ emb,
    const ushort* __restrict__ WT, const float* __restrict__ bias,
    const float* __restrict__ watt,
    ushort* __restrict__ out_bf16, ushort* __restrict__ out2)
{
    __shared__ ushort lds[32 * 328];                 // also reused [256][40] in MODE 1
    const int r0 = blockIdx.x * 32;
    const int n0 = blockIdx.y * 256;
    const int t = threadIdx.x;

    // stage 32 gathered emb rows as bf16, zero-padded to 320
    for (int i = t; i < 32 * 80; i += 256) {
        int r = i / 80, e4 = (i % 80) * 4;
        ushort4 o;
        if (e4 < E) {
            float4 v = *(const float4*)(emb + idx[r0 + r] * E + e4);
            o.x = f2bf(v.x); o.y = f2bf(v.y); o.z = f2bf(v.z); o.w = f2bf(v.w);
        } else o = ushort4{0, 0, 0, 0};
        *(ushort4*)(lds + r * 328 + e4) = o;
    }
    __syncthreads();

    const int w = t >> 6, l = t & 63, lr = l & 15, lc = l >> 4;
    const int nw = n0 + w * 64;
    f32x4 acc[2][4] = {};
    const ushort* wtp = WT + (nw + lr) * EP + lc * 8;
    const ushort* ap  = lds + lr * 328 + lc * 8;

    #pragma unroll 2
    for (int kk = 0; kk < 10; ++kk) {
        bf16x8 a0 = *(const bf16x8*)(ap + kk * 32);
        bf16x8 a1 = *(const bf16x8*)(ap + 16 * 328 + kk * 32);
        #pragma unroll
        for (int nt = 0; nt < 4; ++nt) {
            bf16x8 bfr = *(const bf16x8*)(wtp + nt * 16 * EP + kk * 32);
            acc[0][nt] = MFMA(a0, bfr, acc[0][nt]);
            acc[1][nt] = MFMA(a1, bfr, acc[1][nt]);
        }
    }

    if (MODE == 0) {
        const int b = blockIdx.x;                    // 32 rows == one b
        #pragma unroll
        for (int mt = 0; mt < 2; ++mt)
        #pragma unroll
        for (int nt = 0; nt < 4; ++nt) {
            const int col = nw + nt * 16 + lr;
            const int q = mt * 16 + lc * 4;
            const float bv = bias[col];
            float wv[8];
            *(float4*)(wv)     = *(const float4*)(watt + col * 8);
            *(float4*)(wv + 4) = *(const float4*)(watt + col * 8 + 4);
            #pragma unroll
            for (int r = 0; r < 4; ++r) {
                float v = acc[mt][nt][r] + bv;
                out_bf16[(b * 32 + q + r) * H + col] = f2bf(v);
                #pragma unroll
                for (int g = 0; g < 8; ++g)
                    out2[((b * 8 + g) * 32 + q + r) * H + col] = f2bf(v * wv[g]);
            }
        }
    } else {
        const int b = r0 >> 8, k0 = r0 & 255;
        __syncthreads();                             // done reading A tile
        #pragma unroll
        for (int mt = 0; mt < 2; ++mt)
        #pragma unroll
        for (int nt = 0; nt < 4; ++nt) {
            const int col = nw + nt * 16 + lr;
            const int kq = mt * 16 + lc * 4;
            const float bv = bias[col];
            #pragma unroll
            for (int r = 0; r < 4; ++r) {
                ushort v = f2bf(acc[mt][nt][r] + bv);
                out_bf16[(r0 + kq + r) * H + col] = v;
                lds[(w * 64 + nt * 16 + lr) * 40 + kq + r] = v;   // [256 d][40]
            }
        }
        __syncthreads();
        for (int i = t; i < 1024; i += 256) {        // 256 d-rows x 4 chunks(16B)
            int d = i >> 2, c = i & 3;
            *(bf16x8*)(out2 + b * (H * NK) + (n0 + d) * NK + k0 + c * 8) =
                *(const bf16x8*)(lds + d * 40 + c * 8);
        }
    }
}

// ---------------------------------------------------------------------------
// P2: logits[b,g,q,k] = hqw[b,g] @ hk[b]^T + batt[g]
//     merged heads: one block per b, 8 waves, wave = g (hk[b] shared via L1/L2)
// ---------------------------------------------------------------------------
__global__ __launch_bounds__(512) void logits_mfma(
    const ushort* __restrict__ hqw, const ushort* __restrict__ hk,
    const float* __restrict__ batt, float* __restrict__ logits)
{
    const int b = blockIdx.x;
    const int t = threadIdx.x, g = t >> 6, l = t & 63, lr = l & 15, lc = l >> 4;
    const ushort* ap = hqw + ((b * 8 + g) * 32 + lr) * H + lc * 8;
    const ushort* bp = hk + (b * NK + lr) * H + lc * 8;
    f32x4 acc[2][16] = {};

    #pragma unroll 2
    for (int kk = 0; kk < 32; ++kk) {
        bf16x8 a0 = *(const bf16x8*)(ap + kk * 32);
        bf16x8 a1 = *(const bf16x8*)(ap + 16 * H + kk * 32);
        #pragma unroll
        for (int nt = 0; nt < 16; ++nt) {
            bf16x8 bfr = *(const bf16x8*)(bp + nt * 16 * H + kk * 32);
            acc[0][nt] = MFMA(a0, bfr, acc[0][nt]);
            acc[1][nt] = MFMA(a1, bfr, acc[1][nt]);
        }
    }

    const float bg = batt[g];
    float* lp = logits + (b * 8 + g) * (NQ * NK);
    #pragma unroll
    for (int mt = 0; mt < 2; ++mt)
    #pragma unroll
    for (int nt = 0; nt < 16; ++nt)
    #pragma unroll
    for (int r = 0; r < 4; ++r)
        lp[(mt * 16 + lc * 4 + r) * NK + nt * 16 + lr] = acc[mt][nt][r] + bg;
}

// ---------------------------------------------------------------------------
// P3: joint softmax over 8192 per (b,g); f32 in, bf16 out
// ---------------------------------------------------------------------------
__global__ __launch_bounds__(256) void softmax_kernel(
    const float* __restrict__ logits, ushort* __restrict__ att)
{
    const float* p = logits + blockIdx.x * (NQ * NK);
    ushort* o = att + blockIdx.x * (NQ * NK);
    const int t = threadIdx.x;
    __shared__ float red[4];

    float4 v[8];
    float lm = -1e30f;
    #pragma unroll
    for (int i = 0; i < 8; ++i) {
        v[i] = ((const float4*)p)[t + i * 256];
        lm = fmaxf(lm, fmaxf(fmaxf(v[i].x, v[i].y), fmaxf(v[i].z, v[i].w)));
    }
    #pragma unroll
    for (int off = 32; off; off >>= 1) lm = fmaxf(lm, __shfl_xor(lm, off));
    if ((t & 63) == 0) red[t >> 6] = lm;
    __syncthreads();
    const float gm = fmaxf(fmaxf(red[0], red[1]), fmaxf(red[2], red[3]));

    float ls = 0.f;
    #pragma unroll
    for (int i = 0; i < 8; ++i) {
        v[i].x = __expf(v[i].x - gm); v[i].y = __expf(v[i].y - gm);
        v[i].z = __expf(v[i].z - gm); v[i].w = __expf(v[i].w - gm);
        ls += v[i].x + v[i].y + v[i].z + v[i].w;
    }
    #pragma unroll
    for (int off = 32; off; off >>= 1) ls += __shfl_xor(ls, off);
    __syncthreads();
    if ((t & 63) == 0) red[t >> 6] = ls;
    __syncthreads();
    const float inv = 1.f / (red[0] + red[1] + red[2] + red[3]);
    #pragma unroll
    for (int i = 0; i < 8; ++i) {
        ushort4 u;
        u.x = f2bf(v[i].x * inv); u.y = f2bf(v[i].y * inv);
        u.z = f2bf(v[i].z * inv); u.w = f2bf(v[i].w * inv);
        ((ushort4*)o)[t + i * 256] = u;
    }
}

// ---------------------------------------------------------------------------
// P4: ctx = att[b,g] @ hkT[b], pooled_bf[b,g,d] = bf16(sum_q hq*ctx)
//     merged heads: one block per b, 8 waves, wave = g; A preloaded in regs
// ---------------------------------------------------------------------------
__global__ __launch_bounds__(512) void pooled_mfma(
    const ushort* __restrict__ att, const ushort* __restrict__ hkT,
    const ushort* __restrict__ hq, ushort* __restrict__ pooled_bf)
{
    const int b = blockIdx.x;
    const int t = threadIdx.x, g = t >> 6, l = t & 63, lr = l & 15, lc = l >> 4;
    const ushort* ap = att + ((b * 8 + g) * 32 + lr) * NK + lc * 8;
    const ushort* bp = hkT + b * (H * NK) + lr * NK + lc * 8;
    const ushort* hqb = hq + b * NQ * H;

    bf16x8 pa[2][8];
    #pragma unroll
    for (int mt = 0; mt < 2; ++mt)
    #pragma unroll
    for (int kk = 0; kk < 8; ++kk)
        pa[mt][kk] = *(const bf16x8*)(ap + mt * 16 * NK + kk * 32);

    #pragma unroll 2
    for (int dt = 0; dt < 64; ++dt) {
        f32x4 acc0 = {}, acc1 = {};
        const ushort* bq = bp + dt * 16 * NK;
        #pragma unroll
        for (int kk = 0; kk < 8; ++kk) {
            bf16x8 bfr = *(const bf16x8*)(bq + kk * 32);
            acc0 = MFMA(pa[0][kk], bfr, acc0);
            acc1 = MFMA(pa[1][kk], bfr, acc1);
        }
        const int d = dt * 16 + lr;
        float s = 0.f;
        #pragma unroll
        for (int r = 0; r < 4; ++r) {
            s += bf2f(hqb[(lc * 4 + r) * H + d]) * acc0[r];
            s += bf2f(hqb[(16 + lc * 4 + r) * H + d]) * acc1[r];
        }
        s += __shfl_xor(s, 16);
        s += __shfl_xor(s, 32);
        if (l < 16) pooled_bf[(b * 8 + g) * H + d] = f2bf(s);
    }
}

// ---------------------------------------------------------------------------
// P5: out = pooled_bf[64,8192] @ woutT^T  (MFMA, 64-way k-split)
//     grid(64 ks), 4 waves; wave w covers n-range w*80 (5 n-tiles)
// ---------------------------------------------------------------------------
__global__ __launch_bounds__(256) void outproj_mfma(
    const ushort* __restrict__ pooled_bf, const ushort* __restrict__ woutT,
    float* __restrict__ partial)
{
    const int ks = blockIdx.x;
    const int k0 = ks * 128;
    const int t = threadIdx.x, w = t >> 6, l = t & 63, lr = l & 15, lc = l >> 4;
    const ushort* ap = pooled_bf + lr * KOUT + k0 + lc * 8;
    const ushort* bp = woutT + (w * 80 + lr) * KOUT + k0 + lc * 8;
    f32x4 acc[4][5] = {};

    #pragma unroll
    for (int kk = 0; kk < 4; ++kk) {
        bf16x8 a[4];
        #pragma unroll
        for (int mt = 0; mt < 4; ++mt)
            a[mt] = *(const bf16x8*)(ap + mt * 16 * KOUT + kk * 32);
        #pragma unroll
        for (int nt = 0; nt < 5; ++nt) {
            bf16x8 bfr = *(const bf16x8*)(bp + nt * 16 * KOUT + kk * 32);
            #pragma unroll
            for (int mt = 0; mt < 4; ++mt)
                acc[mt][nt] = MFMA(a[mt], bfr, acc[mt][nt]);
        }
    }

    #pragma unroll
    for (int mt = 0; mt < 4; ++mt)
    #pragma unroll
    for (int nt = 0; nt < 5; ++nt)
    #pragma unroll
    for (int r = 0; r < 4; ++r) {
        const int bb = mt * 16 + lc * 4 + r;
        const int n = w * 80 + nt * 16 + lr;
        partial[(ks * B + bb) * NP + n] = acc[mt][nt][r];
    }
}

// ---------------------------------------------------------------------------
// P6: outv[b,n] = bout[n] + sum_ks partial[ks,b,n]   (76 blocks x 256)
// ---------------------------------------------------------------------------
__global__ __launch_bounds__(256) void reduce_out_kernel(
    const float* __restrict__ partial, const float* __restrict__ bout,
    float* __restrict__ outv)
{
    const int i = blockIdx.x * 256 + threadIdx.x;   // 64*304
    if (i >= B * 304) return;
    const int b = i / 304, n = i % 304;
    float acc = 0.f;
    if (n < NOUT) {
        acc = bout[n];
        for (int ks = 0; ks < 64; ++ks)
            acc += partial[(ks * B + b) * NP + n];
    }
    outv[b * 304 + n] = acc;
}

// ---------------------------------------------------------------------------
// S1: sim[b,a] = outv[b]·glove[a]  — 250 blocks x (16 answers x 64 b)
// ---------------------------------------------------------------------------
__global__ __launch_bounds__(256) void sim_kernel(
    const float* __restrict__ outv, const float* __restrict__ glove,
    float* __restrict__ sim)
{
    __shared__ __align__(16) float ov[64][308];
    __shared__ __align__(16) float gl[16][308];
    const int t = threadIdx.x;
    const int a0 = blockIdx.x * 16;

    for (int i = t; i < 64 * 75; i += 256) {
        int r = i / 75, c = i % 75;
        *(float4*)(&ov[r][c * 4]) = *(const float4*)(&outv[r * 304 + c * 4]);
    }
    for (int i = t; i < 16 * 75; i += 256) {
        int r = i / 75, c = i % 75;
        *(float4*)(&gl[r][c * 4]) = *(const float4*)(&glove[(a0 + r) * NOUT + c * 4]);
    }
    __syncthreads();

    const int a = t & 15, bg = t >> 4;   // 16 answers x 16 b-groups(4 b each)
    float acc[4] = {};
    for (int k4 = 0; k4 < 75; ++k4) {
        float4 g = *(const float4*)(&gl[a][k4 * 4]);
        #pragma unroll
        for (int bi = 0; bi < 4; ++bi) {
            float4 o = *(const float4*)(&ov[bg * 4 + bi][k4 * 4]);
            acc[bi] += g.x * o.x + g.y * o.y + g.z * o.z + g.w * o.w;
        }
    }
    #pragma unroll
    for (int bi = 0; bi < 4; ++bi)
        sim[(bg * 4 + bi) * NANS + a0 + a] = acc[bi];
}

// ---------------------------------------------------------------------------
// S2: per-b log_softmax over 4000, write d_out
// ---------------------------------------------------------------------------
__global__ __launch_bounds__(256) void lsm_kernel(
    const float* __restrict__ sim, float* __restrict__ dout)
{
    const int b = blockIdx.x, t = threadIdx.x;
    const float* p = sim + b * NANS;
    __shared__ float red[4];

    float4 v[4];
    float lm = -1e30f;
    #pragma unroll
    for (int j = 0; j < 4; ++j) {
        int i = t + j * 256;
        if (i < 1000) {
            v[j] = ((const float4*)p)[i];
            lm = fmaxf(lm, fmaxf(fmaxf(v[j].x, v[j].y), fmaxf(v[j].z, v[j].w)));
        }
    }
    #pragma unroll
    for (int off = 32; off; off >>= 1) lm = fmaxf(lm, __shfl_xor(lm, off));
    if ((t & 63) == 0) red[t >> 6] = lm;
    __syncthreads();
    const float gm = fmaxf(fmaxf(red[0], red[1]), fmaxf(red[2], red[3]));

    float ls = 0.f;
    #pragma unroll
    for (int j = 0; j < 4; ++j) {
        int i = t + j * 256;
        if (i < 1000)
            ls += __expf(v[j].x - gm) + __expf(v[j].y - gm) +
                  __expf(v[j].z - gm) + __expf(v[j].w - gm);
    }
    #pragma unroll
    for (int off = 32; off; off >>= 1) ls += __shfl_xor(ls, off);
    __syncthreads();
    if ((t & 63) == 0) red[t >> 6] = ls;
    __syncthreads();
    const float sh = gm + logf(red[0] + red[1] + red[2] + red[3]);

    #pragma unroll
    for (int j = 0; j < 4; ++j) {
        int i = t + j * 256;
        if (i < 1000) {
            float4 o;
            o.x = v[j].x - sh; o.y = v[j].y - sh;
            o.z = v[j].z - sh; o.w = v[j].w - sh;
            ((float4*)(dout + b * NANS))[i] = o;
        }
    }
}

// ---------------------------------------------------------------------------
extern "C" void kernel_launch(void* const* d_in, const int* in_sizes, int n_in,
                              void* d_out, int out_size, void* d_ws, size_t ws_size,
                              hipStream_t stream)
{
    (void)in_sizes; (void)n_in; (void)out_size; (void)ws_size;
    const int*   he_q  = (const int*)  d_in[0];
    const int*   he_k  = (const int*)  d_in[1];
    const float* emb   = (const float*)d_in[2];
    const float* Wq    = (const float*)d_in[3];
    const float* bq    = (const float*)d_in[4];
    const float* Wk    = (const float*)d_in[5];
    const float* bk    = (const float*)d_in[6];
    const float* Watt  = (const float*)d_in[7];
    const float* batt  = (const float*)d_in[8];
    const float* Wout  = (const float*)d_in[9];
    const float* bout  = (const float*)d_in[10];
    const float* glove = (const float*)d_in[11];
    float* out = (float*)d_out;

    ushort* WTq    = (ushort*)d_ws;                  //    327,680 sh
    ushort* WTk    = WTq + 327680;                   //    327,680 sh
    ushort* hq_bf  = WTk + 327680;                   //  2,097,152 sh  [b][q][d]
    ushort* hqw    = hq_bf + 2097152;                // 16,777,216 sh  [b][g][q][d]
    ushort* hk_bf  = hqw + 16777216;                 // 16,777,216 sh  [b][k][d]
    ushort* hkT    = hk_bf + 16777216;               // 16,777,216 sh  [b][d][k]
    ushort* pool_bf= hkT + 16777216;                 //    524,288 sh  [b][g*H+d]
    ushort* woutT  = pool_bf + 524288;               //  2,621,440 sh  [320][8192]
    float*  logit  = (float*)(woutT + 2621440);      //  4,194,304 f32
    ushort* att    = (ushort*)(logit + 4194304);     //  4,194,304 sh
    float*  partial= (float*)(att + 4194304);        //  1,310,720 f32 [64][64][320]
    float*  outv   = partial + 1310720;              //     19,456 f32
    float*  sim    = outv + 19456;                   //    256,000 f32

    prep_wt<<<dim3(16, 2), 256, 0, stream>>>(Wq, Wk, WTq, WTk);
    prep_woutT<<<dim3(128, 5), 256, 0, stream>>>(Wout, woutT);
    proj_mfma<0><<<dim3(64, 4), 256, 0, stream>>>(he_q, emb, WTq, bq, Watt, hq_bf, hqw);
    proj_mfma<1><<<dim3(512, 4), 256, 0, stream>>>(he_k, emb, WTk, bk, Watt, hk_bf, hkT);
    logits_mfma<<<dim3(64), 512, 0, stream>>>(hqw, hk_bf, batt, logit);
    softmax_kernel<<<dim3(512), 256, 0, stream>>>(logit, att);
    pooled_mfma<<<dim3(64), 512, 0, stream>>>(att, hkT, hq_bf, pool_bf);
    outproj_mfma<<<dim3(64), 256, 0, stream>>>(pool_bf, woutT, partial);
    reduce_out_kernel<<<dim3(76), 256, 0, stream>>>(partial, bout, outv);
    sim_kernel<<<dim3(250), 256, 0, stream>>>(outv, glove, sim);
    lsm_kernel<<<dim3(64), 256, 0, stream>>>(sim, out);
}

// Round 5
// 255.338 us; speedup vs baseline: 1.7813x; 1.7813x over previous
//
#include <hip/hip_runtime.h>
#include <math.h>

#define VOCAB 20000
#define E     300
#define EP    320          // padded K for proj GEMM (10 k-steps of 32)
#define H     1024
#define G     8
#define NOUT  300
#define NP    320          // padded N for outproj
#define KOUT  8192         // G*H
#define NANS  4000
#define B     64
#define NQ    32
#define NK    256

typedef __attribute__((ext_vector_type(8))) short bf16x8;
typedef __attribute__((ext_vector_type(4))) float f32x4;

__device__ inline ushort f2bf(float x) {
    union { float f; unsigned u; } c; c.f = x;
    unsigned r = c.u + 0x7FFF + ((c.u >> 16) & 1);   // RNE
    return (ushort)(r >> 16);
}
__device__ inline float bf2f(ushort x) {
    union { unsigned u; float f; } c; c.u = ((unsigned)x) << 16;
    return c.f;
}
#define MFMA(a, b, c) __builtin_amdgcn_mfma_f32_16x16x32_bf16((a), (b), (c), 0, 0, 0)

// ---------------------------------------------------------------------------
// P0: WT[h][e] (bf16, e padded to 320) from W[e][h] f32.  grid (16, 2)
// ---------------------------------------------------------------------------
__global__ __launch_bounds__(256) void prep_wt(
    const float* __restrict__ Wq, const float* __restrict__ Wk,
    ushort* __restrict__ WTq, ushort* __restrict__ WTk)
{
    const float* W = blockIdx.y ? Wk : Wq;
    ushort* WT = blockIdx.y ? WTk : WTq;
    const int h0 = blockIdx.x * 64;
    __shared__ ushort lds[64][EP + 8];
    for (int i = threadIdx.x; i < 64 * EP; i += 256) {
        int e = i / 64, hh = i % 64;                 // coalesced along h
        float v = (e < E) ? W[e * H + h0 + hh] : 0.f;
        lds[hh][e] = f2bf(v);
    }
    __syncthreads();
    for (int i = threadIdx.x; i < 64 * EP; i += 256) {
        int hh = i / EP, e = i % EP;                 // coalesced along e
        WT[(h0 + hh) * EP + e] = lds[hh][e];
    }
}

// ---------------------------------------------------------------------------
// P0b: woutT[n][k] bf16 (n padded to 320) from Wout[k][n] f32. grid (128, 5)
// ---------------------------------------------------------------------------
__global__ __launch_bounds__(256) void prep_woutT(
    const float* __restrict__ Wout, ushort* __restrict__ woutT)
{
    const int k0 = blockIdx.x * 64, n0 = blockIdx.y * 64;
    __shared__ ushort td[64][72];
    for (int i = threadIdx.x; i < 64 * 64; i += 256) {
        int kk = i >> 6, nn = i & 63;
        int n = n0 + nn;
        float v = (n < NOUT) ? Wout[(k0 + kk) * NOUT + n] : 0.f;
        td[nn][kk] = f2bf(v);
    }
    __syncthreads();
    for (int i = threadIdx.x; i < 64 * 8; i += 256) {
        int nn = i >> 3, c = i & 7;
        *(bf16x8*)(woutT + (n0 + nn) * KOUT + k0 + c * 8) =
            *(const bf16x8*)(&td[nn][c * 8]);
    }
}

// ---------------------------------------------------------------------------
// P1: MFMA gather-GEMM  out = emb[idx] @ W + bias   (M-tile 32, N-tile 256)
// MODE 0 (hq): also write hqw[b][g][q][d] = (out * Watt[d][g]) bf16
// MODE 1 (hk): also write hkT[b][d][k] bf16 via LDS transpose bounce
// ---------------------------------------------------------------------------
template <int MODE>
__global__ __launch_bounds__(256) void proj_mfma(
    const int* __restrict__ idx, const float* __restrict__ emb,
    const ushort* __restrict__ WT, const float* __restrict__ bias,
    const float* __restrict__ watt,
    ushort* __restrict__ out_bf16, ushort* __restrict__ out2)
{
    __shared__ ushort lds[32 * 328];                 // also reused [256][40] in MODE 1
    const int r0 = blockIdx.x * 32;
    const int n0 = blockIdx.y * 256;
    const int t = threadIdx.x;

    // stage 32 gathered emb rows as bf16, zero-padded to 320
    for (int i = t; i < 32 * 80; i += 256) {
        int r = i / 80, e4 = (i % 80) * 4;
        ushort4 o;
        if (e4 < E) {
            float4 v = *(const float4*)(emb + idx[r0 + r] * E + e4);
            o.x = f2bf(v.x); o.y = f2bf(v.y); o.z = f2bf(v.z); o.w = f2bf(v.w);
        } else o = ushort4{0, 0, 0, 0};
        *(ushort4*)(lds + r * 328 + e4) = o;
    }
    __syncthreads();

    const int w = t >> 6, l = t & 63, lr = l & 15, lc = l >> 4;
    const int nw = n0 + w * 64;
    f32x4 acc[2][4] = {};
    const ushort* wtp = WT + (nw + lr) * EP + lc * 8;
    const ushort* ap  = lds + lr * 328 + lc * 8;

    #pragma unroll 2
    for (int kk = 0; kk < 10; ++kk) {
        bf16x8 a0 = *(const bf16x8*)(ap + kk * 32);
        bf16x8 a1 = *(const bf16x8*)(ap + 16 * 328 + kk * 32);
        #pragma unroll
        for (int nt = 0; nt < 4; ++nt) {
            bf16x8 bfr = *(const bf16x8*)(wtp + nt * 16 * EP + kk * 32);
            acc[0][nt] = MFMA(a0, bfr, acc[0][nt]);
            acc[1][nt] = MFMA(a1, bfr, acc[1][nt]);
        }
    }

    if (MODE == 0) {
        const int b = blockIdx.x;                    // 32 rows == one b
        #pragma unroll
        for (int mt = 0; mt < 2; ++mt)
        #pragma unroll
        for (int nt = 0; nt < 4; ++nt) {
            const int col = nw + nt * 16 + lr;
            const int q = mt * 16 + lc * 4;
            const float bv = bias[col];
            float wv[8];
            *(float4*)(wv)     = *(const float4*)(watt + col * 8);
            *(float4*)(wv + 4) = *(const float4*)(watt + col * 8 + 4);
            #pragma unroll
            for (int r = 0; r < 4; ++r) {
                float v = acc[mt][nt][r] + bv;
                out_bf16[(b * 32 + q + r) * H + col] = f2bf(v);
                #pragma unroll
                for (int g = 0; g < 8; ++g)
                    out2[((b * 8 + g) * 32 + q + r) * H + col] = f2bf(v * wv[g]);
            }
        }
    } else {
        const int b = r0 >> 8, k0 = r0 & 255;
        __syncthreads();                             // done reading A tile
        #pragma unroll
        for (int mt = 0; mt < 2; ++mt)
        #pragma unroll
        for (int nt = 0; nt < 4; ++nt) {
            const int col = nw + nt * 16 + lr;
            const int kq = mt * 16 + lc * 4;
            const float bv = bias[col];
            #pragma unroll
            for (int r = 0; r < 4; ++r) {
                ushort v = f2bf(acc[mt][nt][r] + bv);
                out_bf16[(r0 + kq + r) * H + col] = v;
                lds[(w * 64 + nt * 16 + lr) * 40 + kq + r] = v;   // [256 d][40]
            }
        }
        __syncthreads();
        for (int i = t; i < 1024; i += 256) {        // 256 d-rows x 4 chunks(16B)
            int d = i >> 2, c = i & 3;
            *(bf16x8*)(out2 + b * (H * NK) + (n0 + d) * NK + k0 + c * 8) =
                *(const bf16x8*)(lds + d * 40 + c * 8);
        }
    }
}

// ---------------------------------------------------------------------------
// P2: logits[b,g,q,k] = hqw[b,g] @ hk[b]^T + batt[g]   block=(b,g), 4 waves
// (same-b blocks are 64 apart in dispatch order -> same XCD -> hk L2 reuse)
// ---------------------------------------------------------------------------
__global__ __launch_bounds__(256) void logits_mfma(
    const ushort* __restrict__ hqw, const ushort* __restrict__ hk,
    const float* __restrict__ batt, float* __restrict__ logits)
{
    const int b = blockIdx.x, g = blockIdx.y;
    const int t = threadIdx.x, w = t >> 6, l = t & 63, lr = l & 15, lc = l >> 4;
    const ushort* ap = hqw + ((b * 8 + g) * 32 + lr) * H + lc * 8;
    const ushort* bp = hk + (b * NK + w * 64 + lr) * H + lc * 8;
    f32x4 acc[2][4] = {};

    #pragma unroll 2
    for (int kk = 0; kk < 32; ++kk) {
        bf16x8 a0 = *(const bf16x8*)(ap + kk * 32);
        bf16x8 a1 = *(const bf16x8*)(ap + 16 * H + kk * 32);
        #pragma unroll
        for (int nt = 0; nt < 4; ++nt) {
            bf16x8 bfr = *(const bf16x8*)(bp + nt * 16 * H + kk * 32);
            acc[0][nt] = MFMA(a0, bfr, acc[0][nt]);
            acc[1][nt] = MFMA(a1, bfr, acc[1][nt]);
        }
    }

    const float bg = batt[g];
    float* lp = logits + (b * 8 + g) * (NQ * NK);
    #pragma unroll
    for (int mt = 0; mt < 2; ++mt)
    #pragma unroll
    for (int nt = 0; nt < 4; ++nt)
    #pragma unroll
    for (int r = 0; r < 4; ++r)
        lp[(mt * 16 + lc * 4 + r) * NK + w * 64 + nt * 16 + lr] = acc[mt][nt][r] + bg;
}

// ---------------------------------------------------------------------------
// P3: joint softmax over 8192 per (b,g); f32 in, bf16 out
// ---------------------------------------------------------------------------
__global__ __launch_bounds__(256) void softmax_kernel(
    const float* __restrict__ logits, ushort* __restrict__ att)
{
    const float* p = logits + blockIdx.x * (NQ * NK);
    ushort* o = att + blockIdx.x * (NQ * NK);
    const int t = threadIdx.x;
    __shared__ float red[4];

    float4 v[8];
    float lm = -1e30f;
    #pragma unroll
    for (int i = 0; i < 8; ++i) {
        v[i] = ((const float4*)p)[t + i * 256];
        lm = fmaxf(lm, fmaxf(fmaxf(v[i].x, v[i].y), fmaxf(v[i].z, v[i].w)));
    }
    #pragma unroll
    for (int off = 32; off; off >>= 1) lm = fmaxf(lm, __shfl_xor(lm, off));
    if ((t & 63) == 0) red[t >> 6] = lm;
    __syncthreads();
    const float gm = fmaxf(fmaxf(red[0], red[1]), fmaxf(red[2], red[3]));

    float ls = 0.f;
    #pragma unroll
    for (int i = 0; i < 8; ++i) {
        v[i].x = __expf(v[i].x - gm); v[i].y = __expf(v[i].y - gm);
        v[i].z = __expf(v[i].z - gm); v[i].w = __expf(v[i].w - gm);
        ls += v[i].x + v[i].y + v[i].z + v[i].w;
    }
    #pragma unroll
    for (int off = 32; off; off >>= 1) ls += __shfl_xor(ls, off);
    __syncthreads();
    if ((t & 63) == 0) red[t >> 6] = ls;
    __syncthreads();
    const float inv = 1.f / (red[0] + red[1] + red[2] + red[3]);
    #pragma unroll
    for (int i = 0; i < 8; ++i) {
        ushort4 u;
        u.x = f2bf(v[i].x * inv); u.y = f2bf(v[i].y * inv);
        u.z = f2bf(v[i].z * inv); u.w = f2bf(v[i].w * inv);
        ((ushort4*)o)[t + i * 256] = u;
    }
}

// ---------------------------------------------------------------------------
// P4: ctx = att[b,g] @ hkT[b], pooled_bf[b,g,d] = bf16(sum_q hq*ctx)
//     block=(b,g), 4 waves x 256 d each (256 thr -> no VGPR cap, acc fits)
// ---------------------------------------------------------------------------
__global__ __launch_bounds__(256) void pooled_mfma(
    const ushort* __restrict__ att, const ushort* __restrict__ hkT,
    const ushort* __restrict__ hq, ushort* __restrict__ pooled_bf)
{
    const int b = blockIdx.x, g = blockIdx.y;
    const int t = threadIdx.x, w = t >> 6, l = t & 63, lr = l & 15, lc = l >> 4;
    const ushort* ap = att + ((b * 8 + g) * 32 + lr) * NK + lc * 8;
    const ushort* bp = hkT + b * (H * NK) + (w * 256 + lr) * NK + lc * 8;
    f32x4 acc[2][16] = {};

    #pragma unroll 2
    for (int kk = 0; kk < 8; ++kk) {
        bf16x8 a0 = *(const bf16x8*)(ap + kk * 32);
        bf16x8 a1 = *(const bf16x8*)(ap + 16 * NK + kk * 32);
        #pragma unroll
        for (int nt = 0; nt < 16; ++nt) {
            bf16x8 bfr = *(const bf16x8*)(bp + nt * 16 * NK + kk * 32);
            acc[0][nt] = MFMA(a0, bfr, acc[0][nt]);
            acc[1][nt] = MFMA(a1, bfr, acc[1][nt]);
        }
    }

    const ushort* hqb = hq + b * NQ * H;
    #pragma unroll
    for (int nt = 0; nt < 16; ++nt) {
        const int d = w * 256 + nt * 16 + lr;
        float s = 0.f;
        #pragma unroll
        for (int mt = 0; mt < 2; ++mt) {
            const int q = mt * 16 + lc * 4;
            #pragma unroll
            for (int r = 0; r < 4; ++r)
                s += bf2f(hqb[(q + r) * H + d]) * acc[mt][nt][r];
        }
        s += __shfl_xor(s, 16);
        s += __shfl_xor(s, 32);
        if (l < 16) pooled_bf[(b * 8 + g) * H + d] = f2bf(s);
    }
}

// ---------------------------------------------------------------------------
// P5: out = pooled_bf[64,8192] @ woutT^T  (MFMA, 64-way k-split)
//     grid(64 ks), 4 waves; wave w covers n-range w*80 (5 n-tiles)
// ---------------------------------------------------------------------------
__global__ __launch_bounds__(256) void outproj_mfma(
    const ushort* __restrict__ pooled_bf, const ushort* __restrict__ woutT,
    float* __restrict__ partial)
{
    const int ks = blockIdx.x;
    const int k0 = ks * 128;
    const int t = threadIdx.x, w = t >> 6, l = t & 63, lr = l & 15, lc = l >> 4;
    const ushort* ap = pooled_bf + lr * KOUT + k0 + lc * 8;
    const ushort* bp = woutT + (w * 80 + lr) * KOUT + k0 + lc * 8;
    f32x4 acc[4][5] = {};

    #pragma unroll
    for (int kk = 0; kk < 4; ++kk) {
        bf16x8 a[4];
        #pragma unroll
        for (int mt = 0; mt < 4; ++mt)
            a[mt] = *(const bf16x8*)(ap + mt * 16 * KOUT + kk * 32);
        #pragma unroll
        for (int nt = 0; nt < 5; ++nt) {
            bf16x8 bfr = *(const bf16x8*)(bp + nt * 16 * KOUT + kk * 32);
            #pragma unroll
            for (int mt = 0; mt < 4; ++mt)
                acc[mt][nt] = MFMA(a[mt], bfr, acc[mt][nt]);
        }
    }

    #pragma unroll
    for (int mt = 0; mt < 4; ++mt)
    #pragma unroll
    for (int nt = 0; nt < 5; ++nt)
    #pragma unroll
    for (int r = 0; r < 4; ++r) {
        const int bb = mt * 16 + lc * 4 + r;
        const int n = w * 80 + nt * 16 + lr;
        partial[(ks * B + bb) * NP + n] = acc[mt][nt][r];
    }
}

// ---------------------------------------------------------------------------
// P6: outv[b,n] = bout[n] + sum_ks partial[ks,b,n]   (76 blocks x 256)
// ---------------------------------------------------------------------------
__global__ __launch_bounds__(256) void reduce_out_kernel(
    const float* __restrict__ partial, const float* __restrict__ bout,
    float* __restrict__ outv)
{
    const int i = blockIdx.x * 256 + threadIdx.x;   // 64*304
    if (i >= B * 304) return;
    const int b = i / 304, n = i % 304;
    float acc = 0.f;
    if (n < NOUT) {
        acc = bout[n];
        for (int ks = 0; ks < 64; ++ks)
            acc += partial[(ks * B + b) * NP + n];
    }
    outv[b * 304 + n] = acc;
}

// ---------------------------------------------------------------------------
// S1: sim[b,a] = outv[b]·glove[a]  — 250 blocks x (16 answers x 64 b)
// ---------------------------------------------------------------------------
__global__ __launch_bounds__(256) void sim_kernel(
    const float* __restrict__ outv, const float* __restrict__ glove,
    float* __restrict__ sim)
{
    __shared__ __align__(16) float ov[64][308];
    __shared__ __align__(16) float gl[16][308];
    const int t = threadIdx.x;
    const int a0 = blockIdx.x * 16;

    for (int i = t; i < 64 * 75; i += 256) {
        int r = i / 75, c = i % 75;
        *(float4*)(&ov[r][c * 4]) = *(const float4*)(&outv[r * 304 + c * 4]);
    }
    for (int i = t; i < 16 * 75; i += 256) {
        int r = i / 75, c = i % 75;
        *(float4*)(&gl[r][c * 4]) = *(const float4*)(&glove[(a0 + r) * NOUT + c * 4]);
    }
    __syncthreads();

    const int a = t & 15, bg = t >> 4;   // 16 answers x 16 b-groups(4 b each)
    float acc[4] = {};
    for (int k4 = 0; k4 < 75; ++k4) {
        float4 g = *(const float4*)(&gl[a][k4 * 4]);
        #pragma unroll
        for (int bi = 0; bi < 4; ++bi) {
            float4 o = *(const float4*)(&ov[bg * 4 + bi][k4 * 4]);
            acc[bi] += g.x * o.x + g.y * o.y + g.z * o.z + g.w * o.w;
        }
    }
    #pragma unroll
    for (int bi = 0; bi < 4; ++bi)
        sim[(bg * 4 + bi) * NANS + a0 + a] = acc[bi];
}

// ---------------------------------------------------------------------------
// S2: per-b log_softmax over 4000, write d_out
// ---------------------------------------------------------------------------
__global__ __launch_bounds__(256) void lsm_kernel(
    const float* __restrict__ sim, float* __restrict__ dout)
{
    const int b = blockIdx.x, t = threadIdx.x;
    const float* p = sim + b * NANS;
    __shared__ float red[4];

    float4 v[4];
    float lm = -1e30f;
    #pragma unroll
    for (int j = 0; j < 4; ++j) {
        int i = t + j * 256;
        if (i < 1000) {
            v[j] = ((const float4*)p)[i];
            lm = fmaxf(lm, fmaxf(fmaxf(v[j].x, v[j].y), fmaxf(v[j].z, v[j].w)));
        }
    }
    #pragma unroll
    for (int off = 32; off; off >>= 1) lm = fmaxf(lm, __shfl_xor(lm, off));
    if ((t & 63) == 0) red[t >> 6] = lm;
    __syncthreads();
    const float gm = fmaxf(fmaxf(red[0], red[1]), fmaxf(red[2], red[3]));

    float ls = 0.f;
    #pragma unroll
    for (int j = 0; j < 4; ++j) {
        int i = t + j * 256;
        if (i < 1000)
            ls += __expf(v[j].x - gm) + __expf(v[j].y - gm) +
                  __expf(v[j].z - gm) + __expf(v[j].w - gm);
    }
    #pragma unroll
    for (int off = 32; off; off >>= 1) ls += __shfl_xor(ls, off);
    __syncthreads();
    if ((t & 63) == 0) red[t >> 6] = ls;
    __syncthreads();
    const float sh = gm + logf(red[0] + red[1] + red[2] + red[3]);

    #pragma unroll
    for (int j = 0; j < 4; ++j) {
        int i = t + j * 256;
        if (i < 1000) {
            float4 o;
            o.x = v[j].x - sh; o.y = v[j].y - sh;
            o.z = v[j].z - sh; o.w = v[j].w - sh;
            ((float4*)(dout + b * NANS))[i] = o;
        }
    }
}

// ---------------------------------------------------------------------------
extern "C" void kernel_launch(void* const* d_in, const int* in_sizes, int n_in,
                              void* d_out, int out_size, void* d_ws, size_t ws_size,
                              hipStream_t stream)
{
    (void)in_sizes; (void)n_in; (void)out_size; (void)ws_size;
    const int*   he_q  = (const int*)  d_in[0];
    const int*   he_k  = (const int*)  d_in[1];
    const float* emb   = (const float*)d_in[2];
    const float* Wq    = (const float*)d_in[3];
    const float* bq    = (const float*)d_in[4];
    const float* Wk    = (const float*)d_in[5];
    const float* bk    = (const float*)d_in[6];
    const float* Watt  = (const float*)d_in[7];
    const float* batt  = (const float*)d_in[8];
    const float* Wout  = (const float*)d_in[9];
    const float* bout  = (const float*)d_in[10];
    const float* glove = (const float*)d_in[11];
    float* out = (float*)d_out;

    ushort* WTq    = (ushort*)d_ws;                  //    327,680 sh
    ushort* WTk    = WTq + 327680;                   //    327,680 sh
    ushort* hq_bf  = WTk + 327680;                   //  2,097,152 sh  [b][q][d]
    ushort* hqw    = hq_bf + 2097152;                // 16,777,216 sh  [b][g][q][d]
    ushort* hk_bf  = hqw + 16777216;                 // 16,777,216 sh  [b][k][d]
    ushort* hkT    = hk_bf + 16777216;               // 16,777,216 sh  [b][d][k]
    ushort* pool_bf= hkT + 16777216;                 //    524,288 sh  [b][g*H+d]
    ushort* woutT  = pool_bf + 524288;               //  2,621,440 sh  [320][8192]
    float*  logit  = (float*)(woutT + 2621440);      //  4,194,304 f32
    ushort* att    = (ushort*)(logit + 4194304);     //  4,194,304 sh
    float*  partial= (float*)(att + 4194304);        //  1,310,720 f32 [64][64][320]
    float*  outv   = partial + 1310720;              //     19,456 f32
    float*  sim    = outv + 19456;                   //    256,000 f32

    prep_wt<<<dim3(16, 2), 256, 0, stream>>>(Wq, Wk, WTq, WTk);
    prep_woutT<<<dim3(128, 5), 256, 0, stream>>>(Wout, woutT);
    proj_mfma<0><<<dim3(64, 4), 256, 0, stream>>>(he_q, emb, WTq, bq, Watt, hq_bf, hqw);
    proj_mfma<1><<<dim3(512, 4), 256, 0, stream>>>(he_k, emb, WTk, bk, Watt, hk_bf, hkT);
    logits_mfma<<<dim3(64, 8), 256, 0, stream>>>(hqw, hk_bf, batt, logit);
    softmax_kernel<<<dim3(512), 256, 0, stream>>>(logit, att);
    pooled_mfma<<<dim3(64, 8), 256, 0, stream>>>(att, hkT, hq_bf, pool_bf);
    outproj_mfma<<<dim3(64), 256, 0, stream>>>(pool_bf, woutT, partial);
    reduce_out_kernel<<<dim3(76), 256, 0, stream>>>(partial, bout, outv);
    sim_kernel<<<dim3(250), 256, 0, stream>>>(outv, glove, sim);
    lsm_kernel<<<dim3(64), 256, 0, stream>>>(sim, out);
}

// Round 6
// 238.865 us; speedup vs baseline: 1.9042x; 1.0690x over previous
//
#include <hip/hip_runtime.h>
#include <math.h>

#define VOCAB 20000
#define E     300
#define EP    320          // padded K for proj GEMM (10 k-steps of 32)
#define H     1024
#define G     8
#define NOUT  300
#define NP    320          // padded N for outproj
#define KOUT  8192         // G*H
#define NANS  4000
#define B     64
#define NQ    32
#define NK    256

typedef __attribute__((ext_vector_type(8))) short bf16x8;
typedef __attribute__((ext_vector_type(4))) float f32x4;

__device__ inline ushort f2bf(float x) {
    union { float f; unsigned u; } c; c.f = x;
    unsigned r = c.u + 0x7FFF + ((c.u >> 16) & 1);   // RNE
    return (ushort)(r >> 16);
}
__device__ inline float bf2f(ushort x) {
    union { unsigned u; float f; } c; c.u = ((unsigned)x) << 16;
    return c.f;
}
#define MFMA(a, b, c) __builtin_amdgcn_mfma_f32_16x16x32_bf16((a), (b), (c), 0, 0, 0)

// ---------------------------------------------------------------------------
// P0: WT[h][e] (bf16, e padded to 320) from W[e][h] f32.  grid (16, 2)
// ---------------------------------------------------------------------------
__global__ __launch_bounds__(256) void prep_wt(
    const float* __restrict__ Wq, const float* __restrict__ Wk,
    ushort* __restrict__ WTq, ushort* __restrict__ WTk)
{
    const float* W = blockIdx.y ? Wk : Wq;
    ushort* WT = blockIdx.y ? WTk : WTq;
    const int h0 = blockIdx.x * 64;
    __shared__ ushort lds[64][EP + 8];
    for (int i = threadIdx.x; i < 64 * EP; i += 256) {
        int e = i / 64, hh = i % 64;                 // coalesced along h
        float v = (e < E) ? W[e * H + h0 + hh] : 0.f;
        lds[hh][e] = f2bf(v);
    }
    __syncthreads();
    for (int i = threadIdx.x; i < 64 * EP; i += 256) {
        int hh = i / EP, e = i % EP;                 // coalesced along e
        WT[(h0 + hh) * EP + e] = lds[hh][e];
    }
}

// ---------------------------------------------------------------------------
// P0b: woutT[n][k] bf16 (n padded to 320) from Wout[k][n] f32. grid (128, 5)
// ---------------------------------------------------------------------------
__global__ __launch_bounds__(256) void prep_woutT(
    const float* __restrict__ Wout, ushort* __restrict__ woutT)
{
    const int k0 = blockIdx.x * 64, n0 = blockIdx.y * 64;
    __shared__ ushort td[64][72];
    for (int i = threadIdx.x; i < 64 * 64; i += 256) {
        int kk = i >> 6, nn = i & 63;
        int n = n0 + nn;
        float v = (n < NOUT) ? Wout[(k0 + kk) * NOUT + n] : 0.f;
        td[nn][kk] = f2bf(v);
    }
    __syncthreads();
    for (int i = threadIdx.x; i < 64 * 8; i += 256) {
        int nn = i >> 3, c = i & 7;
        *(bf16x8*)(woutT + (n0 + nn) * KOUT + k0 + c * 8) =
            *(const bf16x8*)(&td[nn][c * 8]);
    }
}

// ---------------------------------------------------------------------------
// P1: MFMA gather-GEMM  out = emb[idx] @ W + bias   (M-tile 32, N-tile 256)
// MODE 0 (hq): write hq_bf only
// MODE 1 (hk): also write hkT[b][d][k] bf16 via LDS transpose bounce
// ---------------------------------------------------------------------------
template <int MODE>
__global__ __launch_bounds__(256) void proj_mfma(
    const int* __restrict__ idx, const float* __restrict__ emb,
    const ushort* __restrict__ WT, const float* __restrict__ bias,
    ushort* __restrict__ out_bf16, ushort* __restrict__ out2)
{
    __shared__ ushort lds[32 * 328];                 // also reused [256][40] in MODE 1
    const int r0 = blockIdx.x * 32;
    const int n0 = blockIdx.y * 256;
    const int t = threadIdx.x;

    // stage 32 gathered emb rows as bf16, zero-padded to 320
    for (int i = t; i < 32 * 80; i += 256) {
        int r = i / 80, e4 = (i % 80) * 4;
        ushort4 o;
        if (e4 < E) {
            float4 v = *(const float4*)(emb + idx[r0 + r] * E + e4);
            o.x = f2bf(v.x); o.y = f2bf(v.y); o.z = f2bf(v.z); o.w = f2bf(v.w);
        } else o = ushort4{0, 0, 0, 0};
        *(ushort4*)(lds + r * 328 + e4) = o;
    }
    __syncthreads();

    const int w = t >> 6, l = t & 63, lr = l & 15, lc = l >> 4;
    const int nw = n0 + w * 64;
    f32x4 acc[2][4] = {};
    const ushort* wtp = WT + (nw + lr) * EP + lc * 8;
    const ushort* ap  = lds + lr * 328 + lc * 8;

    #pragma unroll 2
    for (int kk = 0; kk < 10; ++kk) {
        bf16x8 a0 = *(const bf16x8*)(ap + kk * 32);
        bf16x8 a1 = *(const bf16x8*)(ap + 16 * 328 + kk * 32);
        #pragma unroll
        for (int nt = 0; nt < 4; ++nt) {
            bf16x8 bfr = *(const bf16x8*)(wtp + nt * 16 * EP + kk * 32);
            acc[0][nt] = MFMA(a0, bfr, acc[0][nt]);
            acc[1][nt] = MFMA(a1, bfr, acc[1][nt]);
        }
    }

    if (MODE == 0) {
        #pragma unroll
        for (int mt = 0; mt < 2; ++mt)
        #pragma unroll
        for (int nt = 0; nt < 4; ++nt) {
            const int col = nw + nt * 16 + lr;
            const int q = mt * 16 + lc * 4;
            const float bv = bias[col];
            #pragma unroll
            for (int r = 0; r < 4; ++r)
                out_bf16[(r0 + q + r) * H + col] = f2bf(acc[mt][nt][r] + bv);
        }
    } else {
        const int b = r0 >> 8, k0 = r0 & 255;
        __syncthreads();                             // done reading A tile
        #pragma unroll
        for (int mt = 0; mt < 2; ++mt)
        #pragma unroll
        for (int nt = 0; nt < 4; ++nt) {
            const int col = nw + nt * 16 + lr;
            const int kq = mt * 16 + lc * 4;
            const float bv = bias[col];
            #pragma unroll
            for (int r = 0; r < 4; ++r) {
                ushort v = f2bf(acc[mt][nt][r] + bv);
                out_bf16[(r0 + kq + r) * H + col] = v;
                lds[(w * 64 + nt * 16 + lr) * 40 + kq + r] = v;   // [256 d][40]
            }
        }
        __syncthreads();
        for (int i = t; i < 1024; i += 256) {        // 256 d-rows x 4 chunks(16B)
            int d = i >> 2, c = i & 3;
            *(bf16x8*)(out2 + b * (H * NK) + (n0 + d) * NK + k0 + c * 8) =
                *(const bf16x8*)(lds + d * 40 + c * 8);
        }
    }
}

// ---------------------------------------------------------------------------
// P2+P3 fused: att[b,g,q,k] = softmax_joint( (hq*watt_g) @ hk^T + batt[g] )
//     block=(b,g), 4 waves; A-fragments scaled on the fly from hq_bf
//     full 32x256 tile lives in acc registers; joint softmax via shfl+LDS
// ---------------------------------------------------------------------------
__global__ __launch_bounds__(256) void attn_mfma(
    const ushort* __restrict__ hq, const ushort* __restrict__ hk,
    const float* __restrict__ watt, const float* __restrict__ batt,
    ushort* __restrict__ att)
{
    const int b = blockIdx.x, g = blockIdx.y;
    const int t = threadIdx.x, w = t >> 6, l = t & 63, lr = l & 15, lc = l >> 4;
    __shared__ float wg[H];
    __shared__ float red[8];

    for (int i = t; i < H; i += 256) wg[i] = watt[i * G + g];
    __syncthreads();

    const ushort* ap = hq + (b * NQ + lr) * H + lc * 8;
    const ushort* bp = hk + (b * NK + w * 64 + lr) * H + lc * 8;
    f32x4 acc[2][4] = {};

    #pragma unroll 2
    for (int kk = 0; kk < 32; ++kk) {
        const int d0 = kk * 32 + lc * 8;
        bf16x8 h0 = *(const bf16x8*)(ap + kk * 32);
        bf16x8 h1 = *(const bf16x8*)(ap + 16 * H + kk * 32);
        f32x4 w0 = *(const f32x4*)(&wg[d0]);
        f32x4 w1 = *(const f32x4*)(&wg[d0 + 4]);
        bf16x8 a0, a1;
        #pragma unroll
        for (int j = 0; j < 4; ++j) {
            a0[j]     = (short)f2bf(bf2f((ushort)h0[j]) * w0[j]);
            a0[j + 4] = (short)f2bf(bf2f((ushort)h0[j + 4]) * w1[j]);
            a1[j]     = (short)f2bf(bf2f((ushort)h1[j]) * w0[j]);
            a1[j + 4] = (short)f2bf(bf2f((ushort)h1[j + 4]) * w1[j]);
        }
        #pragma unroll
        for (int nt = 0; nt < 4; ++nt) {
            bf16x8 bfr = *(const bf16x8*)(bp + nt * 16 * H + kk * 32);
            acc[0][nt] = MFMA(a0, bfr, acc[0][nt]);
            acc[1][nt] = MFMA(a1, bfr, acc[1][nt]);
        }
    }

    // + bias, joint max over all 8192
    const float bg = batt[g];
    float lm = -1e30f;
    #pragma unroll
    for (int mt = 0; mt < 2; ++mt)
    #pragma unroll
    for (int nt = 0; nt < 4; ++nt)
    #pragma unroll
    for (int r = 0; r < 4; ++r) {
        acc[mt][nt][r] += bg;
        lm = fmaxf(lm, acc[mt][nt][r]);
    }
    #pragma unroll
    for (int off = 32; off; off >>= 1) lm = fmaxf(lm, __shfl_xor(lm, off));
    if (l == 0) red[w] = lm;
    __syncthreads();
    const float gm = fmaxf(fmaxf(red[0], red[1]), fmaxf(red[2], red[3]));

    // exp + joint sum
    float ls = 0.f;
    #pragma unroll
    for (int mt = 0; mt < 2; ++mt)
    #pragma unroll
    for (int nt = 0; nt < 4; ++nt)
    #pragma unroll
    for (int r = 0; r < 4; ++r) {
        float e = __expf(acc[mt][nt][r] - gm);
        acc[mt][nt][r] = e;
        ls += e;
    }
    #pragma unroll
    for (int off = 32; off; off >>= 1) ls += __shfl_xor(ls, off);
    if (l == 0) red[4 + w] = ls;
    __syncthreads();
    const float inv = 1.f / (red[4] + red[5] + red[6] + red[7]);

    ushort* op = att + (b * 8 + g) * (NQ * NK);
    #pragma unroll
    for (int mt = 0; mt < 2; ++mt)
    #pragma unroll
    for (int nt = 0; nt < 4; ++nt)
    #pragma unroll
    for (int r = 0; r < 4; ++r)
        op[(mt * 16 + lc * 4 + r) * NK + w * 64 + nt * 16 + lr] =
            f2bf(acc[mt][nt][r] * inv);
}

// ---------------------------------------------------------------------------
// P4: ctx = att[b,g] @ hkT[b], pooled_bf[b,g,d] = bf16(sum_q hq*ctx)
//     block=(b,g), 4 waves x 256 d each (256 thr -> no VGPR cap, acc fits)
// ---------------------------------------------------------------------------
__global__ __launch_bounds__(256) void pooled_mfma(
    const ushort* __restrict__ att, const ushort* __restrict__ hkT,
    const ushort* __restrict__ hq, ushort* __restrict__ pooled_bf)
{
    const int b = blockIdx.x, g = blockIdx.y;
    const int t = threadIdx.x, w = t >> 6, l = t & 63, lr = l & 15, lc = l >> 4;
    const ushort* ap = att + ((b * 8 + g) * 32 + lr) * NK + lc * 8;
    const ushort* bp = hkT + b * (H * NK) + (w * 256 + lr) * NK + lc * 8;
    f32x4 acc[2][16] = {};

    #pragma unroll 2
    for (int kk = 0; kk < 8; ++kk) {
        bf16x8 a0 = *(const bf16x8*)(ap + kk * 32);
        bf16x8 a1 = *(const bf16x8*)(ap + 16 * NK + kk * 32);
        #pragma unroll
        for (int nt = 0; nt < 16; ++nt) {
            bf16x8 bfr = *(const bf16x8*)(bp + nt * 16 * NK + kk * 32);
            acc[0][nt] = MFMA(a0, bfr, acc[0][nt]);
            acc[1][nt] = MFMA(a1, bfr, acc[1][nt]);
        }
    }

    const ushort* hqb = hq + b * NQ * H;
    #pragma unroll
    for (int nt = 0; nt < 16; ++nt) {
        const int d = w * 256 + nt * 16 + lr;
        float s = 0.f;
        #pragma unroll
        for (int mt = 0; mt < 2; ++mt) {
            const int q = mt * 16 + lc * 4;
            #pragma unroll
            for (int r = 0; r < 4; ++r)
                s += bf2f(hqb[(q + r) * H + d]) * acc[mt][nt][r];
        }
        s += __shfl_xor(s, 16);
        s += __shfl_xor(s, 32);
        if (l < 16) pooled_bf[(b * 8 + g) * H + d] = f2bf(s);
    }
}

// ---------------------------------------------------------------------------
// P5: out = pooled_bf[64,8192] @ woutT^T  (MFMA, 64-way k-split)
// ---------------------------------------------------------------------------
__global__ __launch_bounds__(256) void outproj_mfma(
    const ushort* __restrict__ pooled_bf, const ushort* __restrict__ woutT,
    float* __restrict__ partial)
{
    const int ks = blockIdx.x;
    const int k0 = ks * 128;
    const int t = threadIdx.x, w = t >> 6, l = t & 63, lr = l & 15, lc = l >> 4;
    const ushort* ap = pooled_bf + lr * KOUT + k0 + lc * 8;
    const ushort* bp = woutT + (w * 80 + lr) * KOUT + k0 + lc * 8;
    f32x4 acc[4][5] = {};

    #pragma unroll
    for (int kk = 0; kk < 4; ++kk) {
        bf16x8 a[4];
        #pragma unroll
        for (int mt = 0; mt < 4; ++mt)
            a[mt] = *(const bf16x8*)(ap + mt * 16 * KOUT + kk * 32);
        #pragma unroll
        for (int nt = 0; nt < 5; ++nt) {
            bf16x8 bfr = *(const bf16x8*)(bp + nt * 16 * KOUT + kk * 32);
            #pragma unroll
            for (int mt = 0; mt < 4; ++mt)
                acc[mt][nt] = MFMA(a[mt], bfr, acc[mt][nt]);
        }
    }

    #pragma unroll
    for (int mt = 0; mt < 4; ++mt)
    #pragma unroll
    for (int nt = 0; nt < 5; ++nt)
    #pragma unroll
    for (int r = 0; r < 4; ++r) {
        const int bb = mt * 16 + lc * 4 + r;
        const int n = w * 80 + nt * 16 + lr;
        partial[(ks * B + bb) * NP + n] = acc[mt][nt][r];
    }
}

// ---------------------------------------------------------------------------
// P6: outv[b,n] = bout[n] + sum_ks partial[ks,b,n]   (76 blocks x 256)
// ---------------------------------------------------------------------------
__global__ __launch_bounds__(256) void reduce_out_kernel(
    const float* __restrict__ partial, const float* __restrict__ bout,
    float* __restrict__ outv)
{
    const int i = blockIdx.x * 256 + threadIdx.x;   // 64*304
    if (i >= B * 304) return;
    const int b = i / 304, n = i % 304;
    float acc = 0.f;
    if (n < NOUT) {
        acc = bout[n];
        for (int ks = 0; ks < 64; ++ks)
            acc += partial[(ks * B + b) * NP + n];
    }
    outv[b * 304 + n] = acc;
}

// ---------------------------------------------------------------------------
// S1: sim[b,a] = outv[b]·glove[a]  — 250 blocks x (16 answers x 64 b)
// ---------------------------------------------------------------------------
__global__ __launch_bounds__(256) void sim_kernel(
    const float* __restrict__ outv, const float* __restrict__ glove,
    float* __restrict__ sim)
{
    __shared__ __align__(16) float ov[64][308];
    __shared__ __align__(16) float gl[16][308];
    const int t = threadIdx.x;
    const int a0 = blockIdx.x * 16;

    for (int i = t; i < 64 * 75; i += 256) {
        int r = i / 75, c = i % 75;
        *(float4*)(&ov[r][c * 4]) = *(const float4*)(&outv[r * 304 + c * 4]);
    }
    for (int i = t; i < 16 * 75; i += 256) {
        int r = i / 75, c = i % 75;
        *(float4*)(&gl[r][c * 4]) = *(const float4*)(&glove[(a0 + r) * NOUT + c * 4]);
    }
    __syncthreads();

    const int a = t & 15, bg = t >> 4;   // 16 answers x 16 b-groups(4 b each)
    float acc[4] = {};
    for (int k4 = 0; k4 < 75; ++k4) {
        float4 g = *(const float4*)(&gl[a][k4 * 4]);
        #pragma unroll
        for (int bi = 0; bi < 4; ++bi) {
            float4 o = *(const float4*)(&ov[bg * 4 + bi][k4 * 4]);
            acc[bi] += g.x * o.x + g.y * o.y + g.z * o.z + g.w * o.w;
        }
    }
    #pragma unroll
    for (int bi = 0; bi < 4; ++bi)
        sim[(bg * 4 + bi) * NANS + a0 + a] = acc[bi];
}

// ---------------------------------------------------------------------------
// S2: per-b log_softmax over 4000, write d_out
// ---------------------------------------------------------------------------
__global__ __launch_bounds__(256) void lsm_kernel(
    const float* __restrict__ sim, float* __restrict__ dout)
{
    const int b = blockIdx.x, t = threadIdx.x;
    const float* p = sim + b * NANS;
    __shared__ float red[4];

    float4 v[4];
    float lm = -1e30f;
    #pragma unroll
    for (int j = 0; j < 4; ++j) {
        int i = t + j * 256;
        if (i < 1000) {
            v[j] = ((const float4*)p)[i];
            lm = fmaxf(lm, fmaxf(fmaxf(v[j].x, v[j].y), fmaxf(v[j].z, v[j].w)));
        }
    }
    #pragma unroll
    for (int off = 32; off; off >>= 1) lm = fmaxf(lm, __shfl_xor(lm, off));
    if ((t & 63) == 0) red[t >> 6] = lm;
    __syncthreads();
    const float gm = fmaxf(fmaxf(red[0], red[1]), fmaxf(red[2], red[3]));

    float ls = 0.f;
    #pragma unroll
    for (int j = 0; j < 4; ++j) {
        int i = t + j * 256;
        if (i < 1000)
            ls += __expf(v[j].x - gm) + __expf(v[j].y - gm) +
                  __expf(v[j].z - gm) + __expf(v[j].w - gm);
    }
    #pragma unroll
    for (int off = 32; off; off >>= 1) ls += __shfl_xor(ls, off);
    __syncthreads();
    if ((t & 63) == 0) red[t >> 6] = ls;
    __syncthreads();
    const float sh = gm + logf(red[0] + red[1] + red[2] + red[3]);

    #pragma unroll
    for (int j = 0; j < 4; ++j) {
        int i = t + j * 256;
        if (i < 1000) {
            float4 o;
            o.x = v[j].x - sh; o.y = v[j].y - sh;
            o.z = v[j].z - sh; o.w = v[j].w - sh;
            ((float4*)(dout + b * NANS))[i] = o;
        }
    }
}

// ---------------------------------------------------------------------------
extern "C" void kernel_launch(void* const* d_in, const int* in_sizes, int n_in,
                              void* d_out, int out_size, void* d_ws, size_t ws_size,
                              hipStream_t stream)
{
    (void)in_sizes; (void)n_in; (void)out_size; (void)ws_size;
    const int*   he_q  = (const int*)  d_in[0];
    const int*   he_k  = (const int*)  d_in[1];
    const float* emb   = (const float*)d_in[2];
    const float* Wq    = (const float*)d_in[3];
    const float* bq    = (const float*)d_in[4];
    const float* Wk    = (const float*)d_in[5];
    const float* bk    = (const float*)d_in[6];
    const float* Watt  = (const float*)d_in[7];
    const float* batt  = (const float*)d_in[8];
    const float* Wout  = (const float*)d_in[9];
    const float* bout  = (const float*)d_in[10];
    const float* glove = (const float*)d_in[11];
    float* out = (float*)d_out;

    ushort* WTq    = (ushort*)d_ws;                  //    327,680 sh
    ushort* WTk    = WTq + 327680;                   //    327,680 sh
    ushort* hq_bf  = WTk + 327680;                   //  2,097,152 sh  [b][q][d]
    ushort* hk_bf  = hq_bf + 2097152;                // 16,777,216 sh  [b][k][d]
    ushort* hkT    = hk_bf + 16777216;               // 16,777,216 sh  [b][d][k]
    ushort* pool_bf= hkT + 16777216;                 //    524,288 sh  [b][g*H+d]
    ushort* woutT  = pool_bf + 524288;               //  2,621,440 sh  [320][8192]
    ushort* att    = woutT + 2621440;                //  4,194,304 sh
    float*  partial= (float*)(att + 4194304);        //  1,310,720 f32 [64][64][320]
    float*  outv   = partial + 1310720;              //     19,456 f32
    float*  sim    = outv + 19456;                   //    256,000 f32

    prep_wt<<<dim3(16, 2), 256, 0, stream>>>(Wq, Wk, WTq, WTk);
    prep_woutT<<<dim3(128, 5), 256, 0, stream>>>(Wout, woutT);
    proj_mfma<0><<<dim3(64, 4), 256, 0, stream>>>(he_q, emb, WTq, bq, hq_bf, nullptr);
    proj_mfma<1><<<dim3(512, 4), 256, 0, stream>>>(he_k, emb, WTk, bk, hk_bf, hkT);
    attn_mfma<<<dim3(64, 8), 256, 0, stream>>>(hq_bf, hk_bf, Watt, batt, att);
    pooled_mfma<<<dim3(64, 8), 256, 0, stream>>>(att, hkT, hq_bf, pool_bf);
    outproj_mfma<<<dim3(64), 256, 0, stream>>>(pool_bf, woutT, partial);
    reduce_out_kernel<<<dim3(76), 256, 0, stream>>>(partial, bout, outv);
    sim_kernel<<<dim3(250), 256, 0, stream>>>(outv, glove, sim);
    lsm_kernel<<<dim3(64), 256, 0, stream>>>(sim, out);
}